// Round 7
// baseline (35.812 us; speedup 1.0000x reference)
//
#include <hip/hip_runtime.h>

#define SCALE 0.0625f
#define P_OUT 28
#define R_N 128
#define C_N 256
#define HF 50
#define WF 76
#define HW (HF * WF)
#define PP (P_OUT * P_OUT)   // 784
#define CPB 8                // channels per block (R5's best)

// aligned(4): if gfx950's unaligned-access-mode lets LLVM keep a single
// global_load_dwordx2 at 4B alignment we get 1 instr for both x-taps;
// otherwise it legally splits into 2 dword loads (== previous behavior).
typedef float f32x2 __attribute__((ext_vector_type(2), aligned(4)));

// One block per (roi, 8-channel chunk). Thread handles output positions
// t = tid, tid+256, tid+512 (+768 for tid<16). Each adaptive bin covers
// exactly 1 or 2 input elements per dim (len <= 22 < 28), so an output is
// a 2x2 weighted gather = TWO float2 loads (x-taps are adjacent addrs).
// Second elements are cndmask-selected (not multiplied) -> no NaN risk
// from the 1-past-window read, and fewer VALU ops.
__global__ __launch_bounds__(256) void roi_pool_kernel(
    const float* __restrict__ input,   // [N, C, HF, WF]
    const float* __restrict__ rois,    // [R, 5]
    float* __restrict__ out)           // [R, C, P, P]
{
    const int bid = blockIdx.x;
    const int r   = bid >> 5;            // 32 chunks of CPB=8 channels
    const int c0  = (bid & 31) * CPB;
    const int tid = threadIdx.x;

    // ROI params (block-uniform -> scalar loads)
    const float* __restrict__ rp = rois + r * 5;
    const int   nidx = (int)rp[0];
    const float rx1 = rp[1], ry1 = rp[2], rx2 = rp[3], ry2 = rp[4];

    // Window bounds — exact reference integer math
    int ylo = (int)floorf(SCALE * ry1 - 0.5f); if (ylo < 0) ylo = 0;
    int yhi = (int)ceilf(SCALE * ry2 - 0.5f);
    if (yhi == ylo) yhi += 1;
    if (yhi > HF) yhi = HF;
    const int ylen = yhi - ylo;          // 1..22 (< 28)

    int xlo = (int)floorf(SCALE * rx1 - 0.5f); if (xlo < 0) xlo = 0;
    int xhi = (int)ceilf(SCALE * rx2 - 0.5f);
    if (xhi == xlo) xhi += 1;
    if (xhi > WF) xhi = WF;
    const int xlen = xhi - xlo;          // 1..22 (< 28)

    // Per-position params: off (elem offset), dyW (0/WF), xi (0/1 use 2nd
    // x-tap), yi (0/1 use 2nd y-row), w = 1/(cy*cx). Named, no arrays.
#define MAKE_POS(K, TVAL)                                                   \
    int off##K, dyW##K, xi##K, yi##K; float w##K;                           \
    {                                                                       \
        const int t   = (TVAL);                                             \
        const int p   = t / P_OUT;                                          \
        const int q   = t - p * P_OUT;                                      \
        const int yst = ylo + (p * ylen) / P_OUT;                           \
        const int cy  = (ylo + ((p + 1) * ylen + P_OUT - 1) / P_OUT) - yst; \
        const int xst = xlo + (q * xlen) / P_OUT;                           \
        const int cx  = (xlo + ((q + 1) * xlen + P_OUT - 1) / P_OUT) - xst; \
        off##K = yst * WF + xst;                                            \
        dyW##K = (cy - 1) * WF;         /* 0 or WF */                       \
        xi##K  = cx - 1;                /* 0 or 1 */                        \
        yi##K  = cy - 1;                /* 0 or 1 */                        \
        w##K   = 1.0f / (float)(cy * cx);                                   \
    }

    MAKE_POS(0, tid)
    MAKE_POS(1, tid + 256)
    MAKE_POS(2, tid + 512)
    const bool has3 = (tid < PP - 768);   // 16 threads do a 4th position
    MAKE_POS(3, has3 ? (tid + 768) : 0)   // dummy-safe params when !has3

    // Two float2 loads per output: row A pair + row B pair. Second
    // elements gated by cndmask (xi/yi), so stray values never propagate.
#define GATHER(B, K)                                                        \
    ({                                                                      \
        const f32x2 _a = *(const f32x2*)((B) + off##K);                     \
        const f32x2 _b = *(const f32x2*)((B) + off##K + dyW##K);            \
        const float _ra = _a.x + (xi##K ? _a.y : 0.0f);                     \
        const float _rb = _b.x + (xi##K ? _b.y : 0.0f);                     \
        (_ra + (yi##K ? _rb : 0.0f)) * w##K;                                \
    })

    const float* __restrict__ bp =
        input + ((size_t)nidx * C_N + c0) * (size_t)HW;
    float* __restrict__ op =
        out + ((size_t)r * C_N + c0) * (size_t)PP;

    #pragma unroll 2
    for (int c = 0; c < CPB; ++c) {
        const float* __restrict__ B = bp + c * HW;
        float* __restrict__ O = op + c * PP;
        const float v0 = GATHER(B, 0);
        const float v1 = GATHER(B, 1);
        const float v2 = GATHER(B, 2);
        __builtin_nontemporal_store(v0, O + tid);
        __builtin_nontemporal_store(v1, O + tid + 256);
        __builtin_nontemporal_store(v2, O + tid + 512);
        if (has3) {
            const float v3 = GATHER(B, 3);
            __builtin_nontemporal_store(v3, O + tid + 768);
        }
    }
}

extern "C" void kernel_launch(void* const* d_in, const int* in_sizes, int n_in,
                              void* d_out, int out_size, void* d_ws, size_t ws_size,
                              hipStream_t stream) {
    const float* input = (const float*)d_in[0];  // [4,256,50,76]
    const float* rois  = (const float*)d_in[1];  // [128,5]
    float* out = (float*)d_out;                  // [128,256,28,28]

    const int grid = R_N * (C_N / CPB);          // 128 * 32 = 4096 blocks
    roi_pool_kernel<<<grid, 256, 0, stream>>>(input, rois, out);
}

// Round 8
// 28.219 us; speedup vs baseline: 1.2691x; 1.2691x over previous
//
#include <hip/hip_runtime.h>

#define SCALE 0.0625f
#define P_OUT 28
#define R_N 128
#define C_N 256
#define HF 50
#define WF 76
#define HW (HF * WF)
#define PP (P_OUT * P_OUT)     // 784
#define CPB 8                  // channels per block
#define WCOLS 24               // padded window width (xlen<=22, +1 spec tap, pad)
#define WROWS 22               // max window rows (ylen<=22)
#define CH_STRIDE (WROWS * WCOLS)   // 528 floats per channel

// One block per (roi, 8-channel chunk).
// Phase 1: stage the ROI window ([ylen][24] per channel, clamped cols) into
//          LDS with contiguous coalesced loads (~33 lines/channel vs ~240
//          line-touches for direct gathers -> 7x less TA work).
// Phase 2: branchless 2x2 gathers read LDS (adjacent pairs -> ds_read2_b32),
//          overlapping the LDS pipe with the HBM write stream.
// Bin math is exact reference integer arithmetic; every bin covers 1 or 2
// elements per dim (len <= 22 < 28). All taps lie in [ylo,yhi)x[xlo,xhi).
__global__ __launch_bounds__(256) void roi_pool_kernel(
    const float* __restrict__ input,   // [N, C, HF, WF]
    const float* __restrict__ rois,    // [R, 5]
    float* __restrict__ out)           // [R, C, P, P]
{
    __shared__ float lds[CPB * CH_STRIDE];   // 16.9 KB

    const int bid = blockIdx.x;
    const int r   = bid >> 5;            // 32 chunks of CPB=8 channels
    const int c0  = (bid & 31) * CPB;
    const int tid = threadIdx.x;

    // ROI params (block-uniform -> scalar loads)
    const float* __restrict__ rp = rois + r * 5;
    const int   nidx = (int)rp[0];
    const float rx1 = rp[1], ry1 = rp[2], rx2 = rp[3], ry2 = rp[4];

    // Window bounds — exact reference integer math
    int ylo = (int)floorf(SCALE * ry1 - 0.5f); if (ylo < 0) ylo = 0;
    int yhi = (int)ceilf(SCALE * ry2 - 0.5f);
    if (yhi == ylo) yhi += 1;
    if (yhi > HF) yhi = HF;
    const int ylen = yhi - ylo;          // 1..22 (< 28)

    int xlo = (int)floorf(SCALE * rx1 - 0.5f); if (xlo < 0) xlo = 0;
    int xhi = (int)ceilf(SCALE * rx2 - 0.5f);
    if (xhi == xlo) xhi += 1;
    if (xhi > WF) xhi = WF;
    const int xlen = xhi - xlo;          // 1..22 (< 28)

    // ---------------- Phase 1: stage window into LDS ----------------
    const float* __restrict__ bp =
        input + ((size_t)nidx * C_N + c0) * (size_t)HW;

    const int nstage = ylen * WCOLS;     // <= 528
    for (int i = tid; i < nstage; i += 256) {
        const int row = i / WCOLS;
        const int col = i - row * WCOLS;
        int gcol = xlo + col;
        if (gcol > WF - 1) gcol = WF - 1;          // clamp to plane edge
        const int goff = (ylo + row) * WF + gcol;  // rows in [ylo,yhi) in-bounds
        #pragma unroll
        for (int c = 0; c < CPB; ++c)
            lds[c * CH_STRIDE + i] = bp[c * HW + goff];
    }
    __syncthreads();

    // ------------- per-position params (LDS offsets), no arrays -------------
    // offA: first tap; dyO: 0 or WCOLS (second row); xi/yi: use-2nd-tap flags;
    // w = 1/(cy*cx).
#define MAKE_POS(K, TVAL)                                                   \
    int offA##K, dyO##K, xi##K, yi##K; float w##K;                          \
    {                                                                       \
        const int t   = (TVAL);                                             \
        const int p   = t / P_OUT;                                          \
        const int q   = t - p * P_OUT;                                      \
        const int yst = ylo + (p * ylen) / P_OUT;                           \
        const int cy  = (ylo + ((p + 1) * ylen + P_OUT - 1) / P_OUT) - yst; \
        const int xst = xlo + (q * xlen) / P_OUT;                           \
        const int cx  = (xlo + ((q + 1) * xlen + P_OUT - 1) / P_OUT) - xst; \
        offA##K = (yst - ylo) * WCOLS + (xst - xlo);                        \
        dyO##K  = (cy - 1) * WCOLS;      /* 0 or 24 */                      \
        xi##K   = cx - 1;                /* 0 or 1 */                       \
        yi##K   = cy - 1;                /* 0 or 1 */                       \
        w##K    = 1.0f / (float)(cy * cx);                                  \
    }

    MAKE_POS(0, tid)
    MAKE_POS(1, tid + 256)
    MAKE_POS(2, tid + 512)
    const bool has3 = (tid < PP - 768);   // 16 threads do a 4th position
    MAKE_POS(3, has3 ? (tid + 768) : 0)

    // Adjacent-pair LDS reads (mergeable to ds_read2_b32); 2nd elements are
    // cndmask-gated so the speculative +1 tap never propagates.
#define GATHER(L, K)                                                        \
    ({                                                                      \
        const float _a0 = (L)[offA##K];                                     \
        const float _a1 = (L)[offA##K + 1];                                 \
        const float _b0 = (L)[offA##K + dyO##K];                            \
        const float _b1 = (L)[offA##K + dyO##K + 1];                        \
        const float _ra = _a0 + (xi##K ? _a1 : 0.0f);                       \
        const float _rb = _b0 + (xi##K ? _b1 : 0.0f);                       \
        (_ra + (yi##K ? _rb : 0.0f)) * w##K;                                \
    })

    // ---------------- Phase 2: gather from LDS + streaming stores ----------
    float* __restrict__ op =
        out + ((size_t)r * C_N + c0) * (size_t)PP;

    #pragma unroll 2
    for (int c = 0; c < CPB; ++c) {
        const float* __restrict__ L = lds + c * CH_STRIDE;
        float* __restrict__ O = op + c * PP;
        const float v0 = GATHER(L, 0);
        const float v1 = GATHER(L, 1);
        const float v2 = GATHER(L, 2);
        __builtin_nontemporal_store(v0, O + tid);
        __builtin_nontemporal_store(v1, O + tid + 256);
        __builtin_nontemporal_store(v2, O + tid + 512);
        if (has3) {
            const float v3 = GATHER(L, 3);
            __builtin_nontemporal_store(v3, O + tid + 768);
        }
    }
}

extern "C" void kernel_launch(void* const* d_in, const int* in_sizes, int n_in,
                              void* d_out, int out_size, void* d_ws, size_t ws_size,
                              hipStream_t stream) {
    const float* input = (const float*)d_in[0];  // [4,256,50,76]
    const float* rois  = (const float*)d_in[1];  // [128,5]
    float* out = (float*)d_out;                  // [128,256,28,28]

    const int grid = R_N * (C_N / CPB);          // 128 * 32 = 4096 blocks
    roi_pool_kernel<<<grid, 256, 0, stream>>>(input, rois, out);
}

// Round 9
// 25.341 us; speedup vs baseline: 1.4132x; 1.1136x over previous
//
#include <hip/hip_runtime.h>

#define SCALE 0.0625f
#define P_OUT 28
#define R_N 128
#define C_N 256
#define HF 50
#define WF 76
#define HW (HF * WF)
#define PP (P_OUT * P_OUT)     // 784
#define CPB 8                  // channels per block
#define WCOLS 24               // padded window width (xlen<=22, +1 spec tap, pad)
#define WROWS 22               // max window rows (ylen<=22)
#define CH_STRIDE (WROWS * WCOLS)   // 528 floats per channel

typedef float f32x4 __attribute__((ext_vector_type(4)));

// One block per (roi, 8-channel chunk).
// Phase 1 (R8): stage ROI window ([ylen][24] per channel, cols clamped) into
//   LDS with contiguous coalesced global loads.
// Phase 2 (new): quad-per-thread output mapping -> ONE float4 NT store per
//   thread per channel (4096 B per wave-instr, the fill-kernel pattern that
//   achieves 6.7 TB/s) instead of 12.25 scalar-store instrs. Gathers read
//   LDS (adjacent pairs -> ds_read2_b32), so the quad mapping costs nothing
//   on the vmem pipe.
// Bin math is exact reference integer arithmetic; every bin covers 1 or 2
// elements per dim (len <= 22 < 28). All taps lie in the staged window.
__global__ __launch_bounds__(256) void roi_pool_kernel(
    const float* __restrict__ input,   // [N, C, HF, WF]
    const float* __restrict__ rois,    // [R, 5]
    float* __restrict__ out)           // [R, C, P, P]
{
    __shared__ float lds[CPB * CH_STRIDE];   // 16.9 KB

    const int bid = blockIdx.x;
    const int r   = bid >> 5;            // 32 chunks of CPB=8 channels
    const int c0  = (bid & 31) * CPB;
    const int tid = threadIdx.x;

    // ROI params (block-uniform -> scalar loads)
    const float* __restrict__ rp = rois + r * 5;
    const int   nidx = (int)rp[0];
    const float rx1 = rp[1], ry1 = rp[2], rx2 = rp[3], ry2 = rp[4];

    // Window bounds — exact reference integer math
    int ylo = (int)floorf(SCALE * ry1 - 0.5f); if (ylo < 0) ylo = 0;
    int yhi = (int)ceilf(SCALE * ry2 - 0.5f);
    if (yhi == ylo) yhi += 1;
    if (yhi > HF) yhi = HF;
    const int ylen = yhi - ylo;          // 1..22 (< 28)

    int xlo = (int)floorf(SCALE * rx1 - 0.5f); if (xlo < 0) xlo = 0;
    int xhi = (int)ceilf(SCALE * rx2 - 0.5f);
    if (xhi == xlo) xhi += 1;
    if (xhi > WF) xhi = WF;
    const int xlen = xhi - xlo;          // 1..22 (< 28)

    // ---------------- Phase 1: stage window into LDS ----------------
    const float* __restrict__ bp =
        input + ((size_t)nidx * C_N + c0) * (size_t)HW;

    const int nstage = ylen * WCOLS;     // <= 528
    for (int i = tid; i < nstage; i += 256) {
        const int row = i / WCOLS;
        const int col = i - row * WCOLS;
        int gcol = xlo + col;
        if (gcol > WF - 1) gcol = WF - 1;          // clamp to plane edge
        const int goff = (ylo + row) * WF + gcol;  // rows in [ylo,yhi) in-bounds
        #pragma unroll
        for (int c = 0; c < CPB; ++c)
            lds[c * CH_STRIDE + i] = bp[c * HW + goff];
    }
    __syncthreads();

    // ---------------- Phase 2: quad-per-thread LDS gather + float4 NT store
    if (tid >= 196) return;              // no barrier below; 196*4 == 784

    const int p  = tid / 7;              // output row (0..27)
    const int q0 = (tid % 7) * 4;        // first of 4 output cols

    // y bin (shared by the quad)
    const int yst = ylo + (p * ylen) / P_OUT;
    const int cy  = (ylo + ((p + 1) * ylen + P_OUT - 1) / P_OUT) - yst;
    const int rowOff = (yst - ylo) * WCOLS;
    const int dyO    = (cy - 1) * WCOLS;      // 0 or 24
    const int yi     = cy - 1;                // 0 or 1
    const float wy   = 1.0f / (float)cy;

    // x bins for q0..q0+3 (named scalars, no runtime-indexed arrays)
#define MAKE_X(J)                                                           \
    int xoff##J, xi##J; float w##J;                                         \
    {                                                                       \
        const int q  = q0 + (J);                                            \
        const int st = xlo + (q * xlen) / P_OUT;                            \
        const int cx = (xlo + ((q + 1) * xlen + P_OUT - 1) / P_OUT) - st;   \
        xoff##J = st - xlo;                                                 \
        xi##J   = cx - 1;                /* 0 or 1 */                       \
        w##J    = wy / (float)cx;                                           \
    }
    MAKE_X(0) MAKE_X(1) MAKE_X(2) MAKE_X(3)

    // Adjacent-pair LDS reads (mergeable to ds_read2_b32); speculative 2nd
    // elements cndmask-gated so they never propagate.
#define GATHER(L, J)                                                        \
    ({                                                                      \
        const float _a0 = (L)[rowOff + xoff##J];                            \
        const float _a1 = (L)[rowOff + xoff##J + 1];                        \
        const float _b0 = (L)[rowOff + dyO + xoff##J];                      \
        const float _b1 = (L)[rowOff + dyO + xoff##J + 1];                  \
        const float _ra = _a0 + (xi##J ? _a1 : 0.0f);                       \
        const float _rb = _b0 + (xi##J ? _b1 : 0.0f);                       \
        (_ra + (yi ? _rb : 0.0f)) * w##J;                                   \
    })

    float* __restrict__ op =
        out + ((size_t)r * C_N + c0) * (size_t)PP + tid * 4;

    #pragma unroll 2
    for (int c = 0; c < CPB; ++c) {
        const float* __restrict__ L = lds + c * CH_STRIDE;
        f32x4 v;
        v.x = GATHER(L, 0);
        v.y = GATHER(L, 1);
        v.z = GATHER(L, 2);
        v.w = GATHER(L, 3);
        __builtin_nontemporal_store(v, (f32x4*)(op + c * PP));
    }
}

extern "C" void kernel_launch(void* const* d_in, const int* in_sizes, int n_in,
                              void* d_out, int out_size, void* d_ws, size_t ws_size,
                              hipStream_t stream) {
    const float* input = (const float*)d_in[0];  // [4,256,50,76]
    const float* rois  = (const float*)d_in[1];  // [128,5]
    float* out = (float*)d_out;                  // [128,256,28,28]

    const int grid = R_N * (C_N / CPB);          // 128 * 32 = 4096 blocks
    roi_pool_kernel<<<grid, 256, 0, stream>>>(input, rois, out);
}

// Round 10
// 24.802 us; speedup vs baseline: 1.4440x; 1.0218x over previous
//
#include <hip/hip_runtime.h>

#define SCALE 0.0625f
#define P_OUT 28
#define R_N 128
#define C_N 256
#define HF 50
#define WF 76
#define HW (HF * WF)
#define PP (P_OUT * P_OUT)      // 784
#define CPB 8                   // channels per block
#define RXROWS 22               // max window rows (ylen <= 22)
#define RX_CH (RXROWS * P_OUT)  // 616 floats per channel (2464 B, 16B-mult)

typedef float f32x4 __attribute__((ext_vector_type(4)));

// Separable ROI adaptive-avg-pool, one block per (roi, 8-channel chunk).
// Phase A: x-pool directly from global into LDS: Rx[c][row][q] =
//   G[row][xst_q] + xi_q * G[row][xst_q + xi_q]  (unweighted col-sum; the
//   +xi offset is self-clamping so no OOB / no 0*garbage).
// Phase B: quad-per-thread (p, q0..q0+3): out = (Rx[yA][q] + yi*Rx[yB][q])
//   * 1/(cy*cx) via TWO ds_read_b128 (rows are 112B-strided, q0 16B-aligned)
//   + one float4 NT store. DS-pipe instr count drops ~7x vs R9.
// Bin math is exact reference integer arithmetic (bins cover 1-2 elems/dim
// since len <= 22 < 28).
__global__ __launch_bounds__(256) void roi_pool_kernel(
    const float* __restrict__ input,   // [N, C, HF, WF]
    const float* __restrict__ rois,    // [R, 5]
    float* __restrict__ out)           // [R, C, P, P]
{
    __shared__ __align__(16) float rx[CPB * RX_CH];   // 19.7 KB

    const int bid = blockIdx.x;
    const int r   = bid >> 5;            // 32 chunks of CPB=8 channels
    const int c0  = (bid & 31) * CPB;
    const int tid = threadIdx.x;

    // ROI params (block-uniform -> scalar loads)
    const float* __restrict__ rp = rois + r * 5;
    const int   nidx = (int)rp[0];
    const float rx1 = rp[1], ry1 = rp[2], rx2 = rp[3], ry2 = rp[4];

    // Window bounds — exact reference integer math
    int ylo = (int)floorf(SCALE * ry1 - 0.5f); if (ylo < 0) ylo = 0;
    int yhi = (int)ceilf(SCALE * ry2 - 0.5f);
    if (yhi == ylo) yhi += 1;
    if (yhi > HF) yhi = HF;
    const int ylen = yhi - ylo;          // 1..22 (< 28)

    int xlo = (int)floorf(SCALE * rx1 - 0.5f); if (xlo < 0) xlo = 0;
    int xhi = (int)ceilf(SCALE * rx2 - 0.5f);
    if (xhi == xlo) xhi += 1;
    if (xhi > WF) xhi = WF;
    const int xlen = xhi - xlo;          // 1..22 (< 28)

    const float* __restrict__ bp =
        input + ((size_t)nidx * C_N + c0) * (size_t)HW;

    // ---------------- Phase A: x-pooled rows into LDS ----------------
    const int nA = ylen * P_OUT;         // <= 616
    for (int i = tid; i < nA; i += 256) {
        const int row = i / P_OUT;
        const int q   = i - row * P_OUT;
        const int xst = xlo + (q * xlen) / P_OUT;
        const int cx  = (xlo + ((q + 1) * xlen + P_OUT - 1) / P_OUT) - xst;
        const int xi  = cx - 1;          // 0 or 1
        const float fxi = (float)xi;
        const int goff = (ylo + row) * WF + xst;   // in-plane; +xi stays in window
        #pragma unroll
        for (int c = 0; c < CPB; ++c) {
            const float a = bp[c * HW + goff];
            const float b = bp[c * HW + goff + xi];  // == a's addr when cx==1
            rx[c * RX_CH + i] = a + fxi * b;
        }
    }
    __syncthreads();

    // ---------------- Phase B: y-pool + weight + float4 NT store ----------
    if (tid >= 196) return;              // 196 quads * 4 == 784; no barrier below

    const int p  = tid / 7;              // output row (0..27)
    const int q0 = (tid % 7) * 4;        // first of 4 output cols

    const int yst = ylo + (p * ylen) / P_OUT;
    const int cy  = (ylo + ((p + 1) * ylen + P_OUT - 1) / P_OUT) - yst;
    const int yi  = cy - 1;              // 0 or 1
    const float fyi = (float)yi;
    const float wy  = 1.0f / (float)cy;

    const int rowA = (yst - ylo) * P_OUT + q0;     // dword offset in channel
    const int rowB = rowA + yi * P_OUT;            // == rowA when cy==1

    // per-q combined weights (named scalars, no runtime-indexed arrays)
#define MAKE_W(J)                                                           \
    float w##J;                                                             \
    {                                                                       \
        const int q  = q0 + (J);                                            \
        const int st = xlo + (q * xlen) / P_OUT;                            \
        const int cx = (xlo + ((q + 1) * xlen + P_OUT - 1) / P_OUT) - st;   \
        w##J = wy / (float)cx;                                              \
    }
    MAKE_W(0) MAKE_W(1) MAKE_W(2) MAKE_W(3)

    float* __restrict__ op =
        out + ((size_t)r * C_N + c0) * (size_t)PP + tid * 4;

    #pragma unroll
    for (int c = 0; c < CPB; ++c) {
        const float* __restrict__ L = rx + c * RX_CH;
        const f32x4 a = *(const f32x4*)(L + rowA);   // ds_read_b128 (16B-aligned)
        const f32x4 b = *(const f32x4*)(L + rowB);   // ds_read_b128
        f32x4 v;
        v.x = (a.x + fyi * b.x) * w0;
        v.y = (a.y + fyi * b.y) * w1;
        v.z = (a.z + fyi * b.z) * w2;
        v.w = (a.w + fyi * b.w) * w3;
        __builtin_nontemporal_store(v, (f32x4*)(op + c * PP));
    }
}

extern "C" void kernel_launch(void* const* d_in, const int* in_sizes, int n_in,
                              void* d_out, int out_size, void* d_ws, size_t ws_size,
                              hipStream_t stream) {
    const float* input = (const float*)d_in[0];  // [4,256,50,76]
    const float* rois  = (const float*)d_in[1];  // [128,5]
    float* out = (float*)d_out;                  // [128,256,28,28]

    const int grid = R_N * (C_N / CPB);          // 128 * 32 = 4096 blocks
    roi_pool_kernel<<<grid, 256, 0, stream>>>(input, rois, out);
}